// Round 4
// baseline (930.078 us; speedup 1.0000x reference)
//
#include <hip/hip_runtime.h>
#include <cstdint>

// ---------------- problem constants ----------------
#define NPOS 8192              // 8*32*32 spatial positions
#define KTOT 6912              // 27 taps * 256 channels
#define XP_ROWS 11560          // 10*34*34 padded spatial rows
#define XP_SY 34
#define XP_SZ 1156             // 34*34
#define KS 4                   // K-splits
#define KSL 1728               // KTOT/KS
#define NCHUNK 27              // KSL/64

typedef float  facc_t __attribute__((ext_vector_type(4)));
typedef float  f2_t   __attribute__((ext_vector_type(2)));
typedef short  bf8_t  __attribute__((ext_vector_type(8)));   // MFMA bf16 frag (4 VGPRs)
typedef unsigned short ub8_t __attribute__((ext_vector_type(8)));

__device__ __forceinline__ unsigned short f2bf(float f) {
    unsigned u = __float_as_uint(f);
    u = (u + 0x7FFFu + ((u >> 16) & 1u)) >> 16;   // RNE
    return (unsigned short)u;
}

#define GAS(p) ((const __attribute__((address_space(1))) void*)(p))
#define LAS(p) ((__attribute__((address_space(3))) void*)(p))

// ---------------- zero XpA+XpB (adjacent) ----------------
__global__ __launch_bounds__(256) void zero_k(unsigned short* __restrict__ dst) {
    ub8_t zz = {0,0,0,0,0,0,0,0};
    *(ub8_t*)&dst[((size_t)blockIdx.x * 256 + threadIdx.x) * 8] = zz;
}

// ---------------- pad x: fp32 c-major (256,8192) -> interior of XpA[row][256] bf16 ----------------
__global__ __launch_bounds__(256) void pad_x_t(const float* __restrict__ x,
                                               unsigned short* __restrict__ XpA) {
    __shared__ unsigned short T[256 * 33];
    int b = blockIdx.x;
    int z = b >> 5, y = b & 31;
    int t = threadIdx.x;
    int c8 = t >> 5, xv = t & 31;
#pragma unroll 4
    for (int i = 0; i < 32; ++i) {
        int c = i * 8 + c8;
        T[c * 33 + xv] = f2bf(x[c * NPOS + (z << 10) + (y << 5) + xv]);
    }
    __syncthreads();
    int rowb = ((z + 1) * XP_SZ + (y + 1) * XP_SY + 1) * 256;
#pragma unroll 4
    for (int j = 0; j < 32; ++j) {
        XpA[rowb + j * 256 + t] = T[t * 33 + j];
    }
}

// ---------------- all 8 weight transposes in one launch ----------------
__global__ __launch_bounds__(256) void wtrans_all(
    const float* __restrict__ o1, const float* __restrict__ o2,
    const float* __restrict__ o3, const float* __restrict__ o4,
    const float* __restrict__ m1, const float* __restrict__ m2,
    const float* __restrict__ m3, const float* __restrict__ m4,
    unsigned short* __restrict__ wtoff, unsigned short* __restrict__ wtmain) {
    __shared__ float T[6912];
    int b = blockIdx.x, t = threadIdx.x;
    const float* src; unsigned short* dst; int o, O;
    if (b < 512) {
        int L = b >> 7; o = b & 127; O = 108;
        src = (L == 0) ? o1 : (L == 1) ? o2 : (L == 2) ? o3 : o4;
        dst = wtoff + ((size_t)(L * 128 + o)) * KTOT;
    } else {
        int b2 = b - 512;
        int L = b2 >> 8; o = b2 & 255; O = 256;
        src = (L == 0) ? m1 : (L == 1) ? m2 : (L == 2) ? m3 : m4;
        dst = wtmain + ((size_t)(L * 256 + o)) * KTOT;
    }
    if (o < O) {
#pragma unroll 3
        for (int i = 0; i < 27; ++i) T[i * 256 + t] = src[(size_t)o * KTOT + i * 256 + t];
        __syncthreads();
#pragma unroll 3
        for (int i = 0; i < 27; ++i) {
            int kc = i * 256 + t;
            int c = kc & 255, k = kc >> 8;
            dst[kc] = f2bf(T[c * 27 + k]);
        }
    } else {
#pragma unroll 3
        for (int i = 0; i < 27; ++i) dst[i * 256 + t] = 0;
    }
}

// ---------------- fused implicit GEMM (conv or deformable), K-split partials ----------------
// R2: p-tile halved to 32 rows, grid (256, KS) = 1024 blocks = 4 blocks/CU =
// 16 waves/CU (50% occupancy) — was grid-limited at 2 blocks/CU (20% measured).
// Single barrier per chunk, double-buffered Bs[2][32*64] (8 KB).
//   iter sc: [afr sc-1] [stage sc] [MFMA Bs[(sc-1)&1]] [blend->Bs[sc&1]] barrier
// CONV: one global_load_lds width=16 per thread, pre-swizzled SOURCE granule
//       (lane l of wave w -> LDS row w*8+(l>>3), slot l&7; src granule (l&7)^(row&7),
//       an involution matching the MFMA-read XOR swizzle).
// DEFORM: 8-channel reg-staged trilinear blend, packed f2_t math (v_pk_fma_f32).
template<bool DEFORM>
__global__ __launch_bounds__(256, 4)
void fgemm(const unsigned short* __restrict__ Xp,
           const unsigned short* __restrict__ wt,   // [O][KTOT] bf16
           const float* __restrict__ dbuf,          // [108][8192] (DEFORM only)
           float* __restrict__ parts) {
    constexpr int O  = DEFORM ? 256 : 128;
    constexpr int IO = DEFORM ? 4 : 2;              // o-frags (16 rows each) per wave
    __shared__ unsigned short Bs[2][32 * 64] __attribute__((aligned(16)));

    const int t = threadIdx.x;
    const int wave = t >> 6, lane = t & 63;
    const int q = lane >> 4, r = lane & 15;
    const int pbase = blockIdx.x * 32;
    const int ks = blockIdx.y;
    const int kstart = ks * KSL;
    const int obw = wave * (O / 4);

    // deform reg-staging coords: thread -> (row pl = t>>3, 8 channels at csub)
    const int pl = t >> 3;
    const int csub = (t & 7) * 8;
    const int p = pbase + pl;
    const int z = p >> 10, y = (p >> 5) & 31, xx = p & 31;
    const int wrD = pl * 64 + (((t & 7) ^ (pl & 7)) << 3);   // XOR-swizzled write slot

    // conv async-staging coords: wave w covers rows w*8 .. w*8+7
    const int plc = (wave << 3) + (lane >> 3);
    const int cgrp = ((lane & 7) ^ (plc & 7)) << 3;          // pre-swizzled source granule
    const int pC = pbase + plc;
    const int zC = pC >> 10, yC = (pC >> 5) & 31, xC = pC & 31;

    facc_t acc[IO][2];
#pragma unroll
    for (int i = 0; i < IO; ++i)
#pragma unroll
        for (int ip = 0; ip < 2; ++ip) acc[i][ip] = (facc_t){0.f, 0.f, 0.f, 0.f};

    float cw[8];
    int row0 = 0;
    int kprev = -1;

    for (int sc = 0; sc <= NCHUNK; ++sc) {
        const int haveS = (sc < NCHUNK);
        const int haveM = (sc > 0);

        // ---- A-frags for MFMA chunk sc-1 ----
        bf8_t afr[2][IO];
        if (haveM) {
            const int mkc0 = kstart + (sc - 1) * 64;
#pragma unroll
            for (int sl = 0; sl < 2; ++sl)
#pragma unroll
                for (int i = 0; i < IO; ++i)
                    afr[sl][i] = *(const bf8_t*)&wt[(size_t)(obw + i * 16 + r) * KTOT + mkc0 + sl * 32 + q * 8];
        }

        // ---- stage chunk sc ----
        ub8_t st[8];
        if (haveS) {
            const int skc0 = kstart + sc * 64;
            const int sk = skc0 >> 8;
            const int sc0 = skc0 & 255;
            if constexpr (DEFORM) {
                if (sk != kprev) {
                    kprev = sk;
                    const int kd = sk / 9, kh = (sk / 3) % 3, kw = sk % 3;
                    float od  = dbuf[(3 * sk + 0) * NPOS + p];
                    float oh  = dbuf[(3 * sk + 1) * NPOS + p];
                    float ow_ = dbuf[(3 * sk + 2) * NPOS + p];
                    float m   = dbuf[(81 + sk) * NPOS + p];
                    float cd = (float)(z + kd - 1) + od;
                    float ch = (float)(y + kh - 1) + oh;
                    float cx = (float)(xx + kw - 1) + ow_;
                    float fdf = floorf(cd), fhf = floorf(ch), fwf = floorf(cx);
                    float fd = cd - fdf, fh = ch - fhf, fw = cx - fwf;
                    float wz0 = 1.f - fd, wz1 = fd;
                    float wy0 = 1.f - fh, wy1 = fh;
                    float wx0 = 1.f - fw, wx1 = fw;
                    int id, ih, iw;
                    if (fdf < -1.f || fdf >= 8.f)  { wz0 = 0.f; wz1 = 0.f; id = 0; } else id = (int)fdf;
                    if (fhf < -1.f || fhf >= 32.f) { wy0 = 0.f; wy1 = 0.f; ih = 0; } else ih = (int)fhf;
                    if (fwf < -1.f || fwf >= 32.f) { wx0 = 0.f; wx1 = 0.f; iw = 0; } else iw = (int)fwf;
                    wz0 *= m; wz1 *= m;
                    float w00 = wz0 * wy0, w01 = wz0 * wy1, w10 = wz1 * wy0, w11 = wz1 * wy1;
                    cw[0] = w00 * wx0; cw[1] = w00 * wx1;
                    cw[2] = w01 * wx0; cw[3] = w01 * wx1;
                    cw[4] = w10 * wx0; cw[5] = w10 * wx1;
                    cw[6] = w11 * wx0; cw[7] = w11 * wx1;
                    row0 = (id + 1) * XP_SZ + (ih + 1) * XP_SY + (iw + 1);
                }
                const unsigned short* cb = Xp + (size_t)row0 * 256 + sc0 + csub;
#pragma unroll
                for (int j = 0; j < 8; ++j) {
                    const int roff = ((j >> 2) & 1) * XP_SZ + ((j >> 1) & 1) * XP_SY + (j & 1);
                    st[j] = *(const ub8_t*)(cb + roff * 256);
                }
            } else {
                const int kd = sk / 9, kh = (sk / 3) % 3, kw = sk % 3;
                const int rowC = (zC + kd) * XP_SZ + (yC + kh) * XP_SY + (xC + kw);
                unsigned short* lb = &Bs[sc & 1][wave << 9];
                __builtin_amdgcn_global_load_lds(GAS(Xp + (size_t)rowC * 256 + sc0 + cgrp), LAS(lb), 16, 0, 0);
            }
        }

        // ---- MFMA on Bs[(sc-1)&1] ----
        if (haveM) {
            const unsigned short* Bc = Bs[(sc - 1) & 1];
#pragma unroll
            for (int sl = 0; sl < 2; ++sl) {
                bf8_t bfr[2];
#pragma unroll
                for (int ip = 0; ip < 2; ++ip) {
                    int brow = ip * 16 + r;
                    bfr[ip] = *(const bf8_t*)&Bc[brow * 64 + (((sl * 4 + q) ^ (brow & 7)) << 3)];
                }
#pragma unroll
                for (int i = 0; i < IO; ++i)
#pragma unroll
                    for (int ip = 0; ip < 2; ++ip)
                        acc[i][ip] = __builtin_amdgcn_mfma_f32_16x16x32_bf16(afr[sl][i], bfr[ip], acc[i][ip], 0, 0, 0);
            }
        }

        // ---- deform: packed trilinear blend + swizzled LDS write ----
        if constexpr (DEFORM) {
            if (haveS) {
                f2_t av2[4];
#pragma unroll
                for (int e = 0; e < 4; ++e) av2[e] = (f2_t){0.f, 0.f};
#pragma unroll
                for (int j = 0; j < 8; ++j) {
                    const unsigned* dw = (const unsigned*)&st[j];
                    f2_t cwj = {cw[j], cw[j]};
#pragma unroll
                    for (int e = 0; e < 4; ++e) {
                        unsigned d = dw[e];
                        f2_t v = { __uint_as_float(d << 16), __uint_as_float(d & 0xffff0000u) };
                        av2[e] += cwj * v;
                    }
                }
                ub8_t v0;
#pragma unroll
                for (int e = 0; e < 4; ++e) {
                    v0[2 * e]     = f2bf(av2[e][0]);
                    v0[2 * e + 1] = f2bf(av2[e][1]);
                }
                *(ub8_t*)&Bs[sc & 1][wrD] = v0;
            }
        }
        __syncthreads();
    }

    // ---- epilogue: fp32 partials; C/D map row(o)=q*4+reg, col(p)=r [R1/R2-verified] ----
    float* pp = parts + (size_t)ks * O * NPOS;
#pragma unroll
    for (int i = 0; i < IO; ++i)
#pragma unroll
        for (int ip = 0; ip < 2; ++ip)
#pragma unroll
            for (int reg = 0; reg < 4; ++reg) {
                int o = obw + i * 16 + q * 4 + reg;
                int px = pbase + ip * 16 + r;
                pp[(size_t)o * NPOS + px] = acc[i][ip][reg];
            }
}

// ---------------- combine conv partials -> dbuf (bias + sigmoid on o>=81) ----------------
__global__ __launch_bounds__(256) void ccombine(const float* __restrict__ parts,
                                                const float* __restrict__ ob,
                                                float* __restrict__ dbuf) {
    int b = blockIdx.x;                 // 108*8
    int o = b >> 3;
    int p4 = ((b & 7) * 256 + threadIdx.x) * 4;
    float s0 = 0, s1 = 0, s2 = 0, s3 = 0;
#pragma unroll
    for (int s = 0; s < KS; ++s) {
        const float4 v = *(const float4*)&parts[((size_t)(s * 128 + o)) * NPOS + p4];
        s0 += v.x; s1 += v.y; s2 += v.z; s3 += v.w;
    }
    float bv = ob[o];
    s0 += bv; s1 += bv; s2 += bv; s3 += bv;
    if (o >= 81) {
        s0 = 1.f / (1.f + __expf(-s0));
        s1 = 1.f / (1.f + __expf(-s1));
        s2 = 1.f / (1.f + __expf(-s2));
        s3 = 1.f / (1.f + __expf(-s3));
    }
    *(float4*)&dbuf[(size_t)o * NPOS + p4] = make_float4(s0, s1, s2, s3);
}

// ---------------- combine deform partials -> relu bf16, transposed into XpB interior ----------------
__global__ __launch_bounds__(256) void dcombine_h(const float* __restrict__ parts,
                                                  const float* __restrict__ bias,
                                                  unsigned short* __restrict__ XpB) {
    __shared__ unsigned short T[64 * 66];
    int p0 = blockIdx.x * 64, o0 = blockIdx.y * 64;
    int t = threadIdx.x;
    int pl = t & 63, og = t >> 6;
#pragma unroll 4
    for (int j = 0; j < 16; ++j) {
        int ol = og * 16 + j;
        float s = 0.f;
#pragma unroll
        for (int sp = 0; sp < KS; ++sp)
            s += parts[((size_t)(sp * 256 + o0 + ol)) * NPOS + p0 + pl];
        s += bias[o0 + ol];
        T[ol * 66 + pl] = f2bf(fmaxf(s, 0.f));
    }
    __syncthreads();
    int c = t & 63, pr = t >> 6;
#pragma unroll 4
    for (int j = 0; j < 16; ++j) {
        int pl2 = j * 4 + pr;
        int pg = p0 + pl2;
        int zz = pg >> 10, yy = (pg >> 5) & 31, xv = pg & 31;
        int row = (zz + 1) * XP_SZ + (yy + 1) * XP_SY + xv + 1;
        XpB[(size_t)row * 256 + o0 + c] = T[c * 66 + pl2];
    }
}

// ---------------- final combine -> fp32 o-major output (bias only) ----------------
__global__ __launch_bounds__(256) void dcombine_out(const float* __restrict__ parts,
                                                    const float* __restrict__ bias,
                                                    float* __restrict__ out) {
    int b = blockIdx.x;                 // 256*8
    int o = b >> 3;
    int p4 = ((b & 7) * 256 + threadIdx.x) * 4;
    float s0 = 0, s1 = 0, s2 = 0, s3 = 0;
#pragma unroll
    for (int s = 0; s < KS; ++s) {
        const float4 v = *(const float4*)&parts[((size_t)(s * 256 + o)) * NPOS + p4];
        s0 += v.x; s1 += v.y; s2 += v.z; s3 += v.w;
    }
    float bv = bias[o];
    *(float4*)&out[(size_t)o * NPOS + p4] = make_float4(s0 + bv, s1 + bv, s2 + bv, s3 + bv);
}

// ---------------- host orchestration ----------------
extern "C" void kernel_launch(void* const* d_in, const int* in_sizes, int n_in,
                              void* d_out, int out_size, void* d_ws, size_t ws_size,
                              hipStream_t stream) {
    const float* x      = (const float*)d_in[0];
    const float* ow1    = (const float*)d_in[1];
    const float* ob1    = (const float*)d_in[2];
    const float* w1     = (const float*)d_in[3];
    const float* b1     = (const float*)d_in[4];
    const float* ow2    = (const float*)d_in[5];
    const float* ob2    = (const float*)d_in[6];
    const float* w2     = (const float*)d_in[7];
    const float* b2     = (const float*)d_in[8];
    const float* ow3    = (const float*)d_in[9];
    const float* ob3    = (const float*)d_in[10];
    const float* w3     = (const float*)d_in[11];
    const float* b3     = (const float*)d_in[12];
    const float* defo_w = (const float*)d_in[13];
    const float* defo_b = (const float*)d_in[14];
    const float* c3d_w  = (const float*)d_in[15];
    const float* c3d_b  = (const float*)d_in[16];
    float* out = (float*)d_out;

    // workspace carve-up (~70 MB)
    unsigned short* XpA    = (unsigned short*)d_ws;          // 2,959,360 us
    unsigned short* XpB    = XpA + (size_t)XP_ROWS * 256;    // 2,959,360 us (adjacent for zero_k)
    unsigned short* wtoff  = XpB + (size_t)XP_ROWS * 256;    // 4*128*6912
    unsigned short* wtmain = wtoff + (size_t)4 * 128 * KTOT; // 4*256*6912
    float* dbufp = (float*)(wtmain + (size_t)4 * 256 * KTOT);// 108*8192 fp32
    float* parts = dbufp + (size_t)108 * NPOS;               // 4*256*8192 fp32

    const dim3 blk(256);
    const dim3 gG(256, KS);

    zero_k<<<2890, blk, 0, stream>>>(XpA);                   // zeros XpA + XpB
    pad_x_t<<<256, blk, 0, stream>>>(x, XpA);
    wtrans_all<<<1536, blk, 0, stream>>>(ow1, ow2, ow3, defo_w, w1, w2, w3, c3d_w, wtoff, wtmain);

    const float* cbias[4] = {ob1, ob2, ob3, defo_b};
    const float* dbias[4] = {b1, b2, b3, c3d_b};

    for (int L = 0; L < 4; ++L) {
        const unsigned short* featConv = (L == 0) ? XpA : XpB;          // conv input = h_{L-1}
        const unsigned short* featDef  = (L == 3) ? XpA : featConv;     // final deform samples original x
        fgemm<false><<<gG, blk, 0, stream>>>(featConv, wtoff + (size_t)L * 128 * KTOT, nullptr, parts);
        ccombine<<<864, blk, 0, stream>>>(parts, cbias[L], dbufp);
        fgemm<true><<<gG, blk, 0, stream>>>(featDef, wtmain + (size_t)L * 256 * KTOT, dbufp, parts);
        if (L < 3) dcombine_h<<<dim3(128, 4), blk, 0, stream>>>(parts, dbias[L], XpB);
        else       dcombine_out<<<2048, blk, 0, stream>>>(parts, dbias[L], out);
    }
}

// Round 5
// 868.929 us; speedup vs baseline: 1.0704x; 1.0704x over previous
//
#include <hip/hip_runtime.h>
#include <cstdint>

// ---------------- problem constants ----------------
#define NPOS 8192              // 8*32*32 spatial positions
#define KTOT 6912              // 27 taps * 256 channels
#define XP_ROWS 11560          // 10*34*34 padded spatial rows
#define XP_SY 34
#define XP_SZ 1156             // 34*34
#define KS 6                   // K-splits (R4: 4->6; 768 blocks = 3/CU, was grid-limited at 2/CU)
#define KSL 1152               // KTOT/KS
#define NCHUNK 18              // KSL/64

typedef float  facc_t __attribute__((ext_vector_type(4)));
typedef short  bf8_t  __attribute__((ext_vector_type(8)));   // MFMA bf16 frag (4 VGPRs)
typedef unsigned short ub8_t __attribute__((ext_vector_type(8)));

__device__ __forceinline__ unsigned short f2bf(float f) {
    unsigned u = __float_as_uint(f);
    u = (u + 0x7FFFu + ((u >> 16) & 1u)) >> 16;   // RNE
    return (unsigned short)u;
}
__device__ __forceinline__ float bf2f(unsigned short u) {
    return __uint_as_float(((unsigned)u) << 16);
}

// ---------------- zero XpA+XpB (adjacent, 2*2,959,360 us) ----------------
__global__ __launch_bounds__(256) void zero_k(unsigned short* __restrict__ dst) {
    ub8_t zz = {0,0,0,0,0,0,0,0};
    *(ub8_t*)&dst[((size_t)blockIdx.x * 256 + threadIdx.x) * 8] = zz;
}

// ---------------- pad x: fp32 c-major (256,8192) -> interior of XpA[row][256] bf16 ----------------
// grid 256 = (z*32+y); LDS transpose so both sides are coalesced
__global__ __launch_bounds__(256) void pad_x_t(const float* __restrict__ x,
                                               unsigned short* __restrict__ XpA) {
    __shared__ unsigned short T[256 * 33];
    int b = blockIdx.x;
    int z = b >> 5, y = b & 31;
    int t = threadIdx.x;
    int c8 = t >> 5, xv = t & 31;
#pragma unroll 4
    for (int i = 0; i < 32; ++i) {
        int c = i * 8 + c8;
        T[c * 33 + xv] = f2bf(x[c * NPOS + (z << 10) + (y << 5) + xv]);
    }
    __syncthreads();
    int rowb = ((z + 1) * XP_SZ + (y + 1) * XP_SY + 1) * 256;
#pragma unroll 4
    for (int j = 0; j < 32; ++j) {
        XpA[rowb + j * 256 + t] = T[t * 33 + j];
    }
}

// ---------------- all 8 weight transposes in one launch ----------------
// src w[o][c][k] fp32 (row = 6912 contiguous) -> dst[o][k*256+c] bf16
__global__ __launch_bounds__(256) void wtrans_all(
    const float* __restrict__ o1, const float* __restrict__ o2,
    const float* __restrict__ o3, const float* __restrict__ o4,
    const float* __restrict__ m1, const float* __restrict__ m2,
    const float* __restrict__ m3, const float* __restrict__ m4,
    unsigned short* __restrict__ wtoff, unsigned short* __restrict__ wtmain) {
    __shared__ float T[6912];
    int b = blockIdx.x, t = threadIdx.x;
    const float* src; unsigned short* dst; int o, O;
    if (b < 512) {
        int L = b >> 7; o = b & 127; O = 108;
        src = (L == 0) ? o1 : (L == 1) ? o2 : (L == 2) ? o3 : o4;
        dst = wtoff + ((size_t)(L * 128 + o)) * KTOT;
    } else {
        int b2 = b - 512;
        int L = b2 >> 8; o = b2 & 255; O = 256;
        src = (L == 0) ? m1 : (L == 1) ? m2 : (L == 2) ? m3 : m4;
        dst = wtmain + ((size_t)(L * 256 + o)) * KTOT;
    }
    if (o < O) {
#pragma unroll 3
        for (int i = 0; i < 27; ++i) T[i * 256 + t] = src[(size_t)o * KTOT + i * 256 + t];
        __syncthreads();
#pragma unroll 3
        for (int i = 0; i < 27; ++i) {
            int kc = i * 256 + t;
            int c = kc & 255, k = kc >> 8;
            dst[kc] = f2bf(T[c * 27 + k]);
        }
    } else {
#pragma unroll 3
        for (int i = 0; i < 27; ++i) dst[i * 256 + t] = 0;
    }
}

// ---------------- fused implicit GEMM (conv or deformable), K-split partials ----------------
// parts[ks][O][8192] += A[o][kc]*B[p][kc] over kc in [ks*KSL, +KSL)
// DEFORM: B staged per chunk by on-the-fly trilinear sampling from Xp (bf16 pos-major, padded)
// CONV:   B staged by integer-tap row copy from Xp
// (766-us verified structure; only KS changed 4->6.)
template<bool DEFORM>
__global__ __launch_bounds__(256)
void fgemm(const unsigned short* __restrict__ Xp,
           const unsigned short* __restrict__ wt,   // [O][KTOT] bf16
           const float* __restrict__ dbuf,          // [108][8192] (DEFORM only)
           float* __restrict__ parts) {
    constexpr int O   = DEFORM ? 256 : 128;
    constexpr int PWN = DEFORM ? 4 : 2;             // p-frags per wave
    __shared__ unsigned short Bs[64 * 64] __attribute__((aligned(16)));

    const int t = threadIdx.x;
    const int wave = t >> 6, lane = t & 63;
    const int q = lane >> 4, r = lane & 15;
    const int pbase = blockIdx.x * 64;
    const int ks = blockIdx.y;
    const int kstart = ks * KSL;

    const int obw = DEFORM ? (wave * 64) : ((wave >> 1) * 64);
    const int pfb = DEFORM ? 0 : ((wave & 1) * 32);

    // staging coords: thread -> (p_local = t>>2, 16 channels at csub)
    const int pl = t >> 2;
    const int csub = (t & 3) * 16;
    const int p = pbase + pl;
    const int z = p >> 10, y = (p >> 5) & 31, xx = p & 31;
    const int g0 = (t & 3) * 2;
    const int wr0 = pl * 64 + ((g0 ^ (pl & 7)) << 3);
    const int wr1 = pl * 64 + (((g0 + 1) ^ (pl & 7)) << 3);

    facc_t acc[4][PWN];
#pragma unroll
    for (int i = 0; i < 4; ++i)
#pragma unroll
        for (int ip = 0; ip < PWN; ++ip) acc[i][ip] = (facc_t){0.f, 0.f, 0.f, 0.f};

    float cw[8];
    int row0 = 0;
    int kprev = -1;

    for (int chunk = 0; chunk < NCHUNK; ++chunk) {
        const int kc0 = kstart + chunk * 64;
        const int k = kc0 >> 8;
        const int c0 = kc0 & 255;
        const int kd = k / 9, kh = (k / 3) % 3, kw = k % 3;

        // ---- A-fragments straight from global (L2-resident weights) ----
        bf8_t afr[2][4];
#pragma unroll
        for (int sl = 0; sl < 2; ++sl)
#pragma unroll
            for (int i = 0; i < 4; ++i)
                afr[sl][i] = *(const bf8_t*)&wt[(size_t)(obw + i * 16 + r) * KTOT + kc0 + sl * 32 + q * 8];

        // ---- B staging ----
        if (DEFORM) {
            if (k != kprev) {
                kprev = k;
                float od  = dbuf[(3 * k + 0) * NPOS + p];
                float oh  = dbuf[(3 * k + 1) * NPOS + p];
                float ow_ = dbuf[(3 * k + 2) * NPOS + p];
                float m   = dbuf[(81 + k) * NPOS + p];
                float cd = (float)(z + kd - 1) + od;
                float ch = (float)(y + kh - 1) + oh;
                float cx = (float)(xx + kw - 1) + ow_;
                float fdf = floorf(cd), fhf = floorf(ch), fwf = floorf(cx);
                float fd = cd - fdf, fh = ch - fhf, fw = cx - fwf;
                float wz0 = 1.f - fd, wz1 = fd;
                float wy0 = 1.f - fh, wy1 = fh;
                float wx0 = 1.f - fw, wx1 = fw;
                int id, ih, iw;
                if (fdf < -1.f || fdf >= 8.f)  { wz0 = 0.f; wz1 = 0.f; id = 0; } else id = (int)fdf;
                if (fhf < -1.f || fhf >= 32.f) { wy0 = 0.f; wy1 = 0.f; ih = 0; } else ih = (int)fhf;
                if (fwf < -1.f || fwf >= 32.f) { wx0 = 0.f; wx1 = 0.f; iw = 0; } else iw = (int)fwf;
                wz0 *= m; wz1 *= m;
                float w00 = wz0 * wy0, w01 = wz0 * wy1, w10 = wz1 * wy0, w11 = wz1 * wy1;
                cw[0] = w00 * wx0; cw[1] = w00 * wx1;
                cw[2] = w01 * wx0; cw[3] = w01 * wx1;
                cw[4] = w10 * wx0; cw[5] = w10 * wx1;
                cw[6] = w11 * wx0; cw[7] = w11 * wx1;
                row0 = (id + 1) * XP_SZ + (ih + 1) * XP_SY + (iw + 1);
            }
            float av[16];
#pragma unroll
            for (int e = 0; e < 16; ++e) av[e] = 0.f;
            const unsigned short* cb = Xp + (size_t)row0 * 256 + c0 + csub;
#pragma unroll
            for (int j = 0; j < 8; ++j) {
                const int roff = ((j >> 2) & 1) * XP_SZ + ((j >> 1) & 1) * XP_SY + (j & 1);
                ub8_t lo = *(const ub8_t*)(cb + roff * 256);
                ub8_t hi = *(const ub8_t*)(cb + roff * 256 + 8);
#pragma unroll
                for (int e = 0; e < 8; ++e) {
                    av[e]     += cw[j] * bf2f(lo[e]);
                    av[8 + e] += cw[j] * bf2f(hi[e]);
                }
            }
            ub8_t v0, v1;
#pragma unroll
            for (int e = 0; e < 8; ++e) { v0[e] = f2bf(av[e]); v1[e] = f2bf(av[8 + e]); }
            *(ub8_t*)&Bs[wr0] = v0;
            *(ub8_t*)&Bs[wr1] = v1;
        } else {
            int row = (z + kd) * XP_SZ + (y + kh) * XP_SY + (xx + kw);
            ub8_t lo = *(const ub8_t*)&Xp[(size_t)row * 256 + c0 + csub];
            ub8_t hi = *(const ub8_t*)&Xp[(size_t)row * 256 + c0 + csub + 8];
            *(ub8_t*)&Bs[wr0] = lo;
            *(ub8_t*)&Bs[wr1] = hi;
        }
        __syncthreads();

        // ---- MFMA ----
#pragma unroll
        for (int sl = 0; sl < 2; ++sl) {
            bf8_t bfr[PWN];
#pragma unroll
            for (int ip = 0; ip < PWN; ++ip) {
                int brow = pfb + ip * 16 + r;
                bfr[ip] = *(const bf8_t*)&Bs[brow * 64 + (((sl * 4 + q) ^ (brow & 7)) << 3)];
            }
#pragma unroll
            for (int i = 0; i < 4; ++i)
#pragma unroll
                for (int ip = 0; ip < PWN; ++ip)
                    acc[i][ip] = __builtin_amdgcn_mfma_f32_16x16x32_bf16(afr[sl][i], bfr[ip], acc[i][ip], 0, 0, 0);
        }
        __syncthreads();
    }

    // ---- epilogue: fp32 partials; C/D map row(o)=q*4+reg, col(p)=r [R1/R2-verified] ----
    float* pp = parts + (size_t)ks * O * NPOS;
#pragma unroll
    for (int i = 0; i < 4; ++i)
#pragma unroll
        for (int ip = 0; ip < PWN; ++ip)
#pragma unroll
            for (int reg = 0; reg < 4; ++reg) {
                int o = obw + i * 16 + q * 4 + reg;
                int px = pbase + pfb + ip * 16 + r;
                pp[(size_t)o * NPOS + px] = acc[i][ip][reg];
            }
}

// ---------------- combine conv partials -> dbuf (bias + sigmoid on o>=81) ----------------
__global__ __launch_bounds__(256) void ccombine(const float* __restrict__ parts,
                                                const float* __restrict__ ob,
                                                float* __restrict__ dbuf) {
    int b = blockIdx.x;                 // 108*8
    int o = b >> 3;
    int p4 = ((b & 7) * 256 + threadIdx.x) * 4;
    float s0 = 0, s1 = 0, s2 = 0, s3 = 0;
#pragma unroll
    for (int s = 0; s < KS; ++s) {
        const float4 v = *(const float4*)&parts[((size_t)(s * 128 + o)) * NPOS + p4];
        s0 += v.x; s1 += v.y; s2 += v.z; s3 += v.w;
    }
    float bv = ob[o];
    s0 += bv; s1 += bv; s2 += bv; s3 += bv;
    if (o >= 81) {
        s0 = 1.f / (1.f + __expf(-s0));
        s1 = 1.f / (1.f + __expf(-s1));
        s2 = 1.f / (1.f + __expf(-s2));
        s3 = 1.f / (1.f + __expf(-s3));
    }
    *(float4*)&dbuf[(size_t)o * NPOS + p4] = make_float4(s0, s1, s2, s3);
}

// ---------------- combine deform partials -> relu bf16, transposed into XpB interior ----------------
// grid (128 p-tiles, 4 o-tiles)
__global__ __launch_bounds__(256) void dcombine_h(const float* __restrict__ parts,
                                                  const float* __restrict__ bias,
                                                  unsigned short* __restrict__ XpB) {
    __shared__ unsigned short T[64 * 66];
    int p0 = blockIdx.x * 64, o0 = blockIdx.y * 64;
    int t = threadIdx.x;
    int pl = t & 63, og = t >> 6;
#pragma unroll 4
    for (int j = 0; j < 16; ++j) {
        int ol = og * 16 + j;
        float s = 0.f;
#pragma unroll
        for (int sp = 0; sp < KS; ++sp)
            s += parts[((size_t)(sp * 256 + o0 + ol)) * NPOS + p0 + pl];
        s += bias[o0 + ol];
        T[ol * 66 + pl] = f2bf(fmaxf(s, 0.f));
    }
    __syncthreads();
    int c = t & 63, pr = t >> 6;
#pragma unroll 4
    for (int j = 0; j < 16; ++j) {
        int pl2 = j * 4 + pr;
        int pg = p0 + pl2;
        int zz = pg >> 10, yy = (pg >> 5) & 31, xv = pg & 31;
        int row = (zz + 1) * XP_SZ + (yy + 1) * XP_SY + xv + 1;
        XpB[(size_t)row * 256 + o0 + c] = T[c * 66 + pl2];
    }
}

// ---------------- final combine -> fp32 o-major output (bias only) ----------------
__global__ __launch_bounds__(256) void dcombine_out(const float* __restrict__ parts,
                                                    const float* __restrict__ bias,
                                                    float* __restrict__ out) {
    int b = blockIdx.x;                 // 256*8
    int o = b >> 3;
    int p4 = ((b & 7) * 256 + threadIdx.x) * 4;
    float s0 = 0, s1 = 0, s2 = 0, s3 = 0;
#pragma unroll
    for (int s = 0; s < KS; ++s) {
        const float4 v = *(const float4*)&parts[((size_t)(s * 256 + o)) * NPOS + p4];
        s0 += v.x; s1 += v.y; s2 += v.z; s3 += v.w;
    }
    float bv = bias[o];
    *(float4*)&out[(size_t)o * NPOS + p4] = make_float4(s0 + bv, s1 + bv, s2 + bv, s3 + bv);
}

// ---------------- host orchestration ----------------
extern "C" void kernel_launch(void* const* d_in, const int* in_sizes, int n_in,
                              void* d_out, int out_size, void* d_ws, size_t ws_size,
                              hipStream_t stream) {
    const float* x      = (const float*)d_in[0];
    const float* ow1    = (const float*)d_in[1];
    const float* ob1    = (const float*)d_in[2];
    const float* w1     = (const float*)d_in[3];
    const float* b1     = (const float*)d_in[4];
    const float* ow2    = (const float*)d_in[5];
    const float* ob2    = (const float*)d_in[6];
    const float* w2     = (const float*)d_in[7];
    const float* b2     = (const float*)d_in[8];
    const float* ow3    = (const float*)d_in[9];
    const float* ob3    = (const float*)d_in[10];
    const float* w3     = (const float*)d_in[11];
    const float* b3     = (const float*)d_in[12];
    const float* defo_w = (const float*)d_in[13];
    const float* defo_b = (const float*)d_in[14];
    const float* c3d_w  = (const float*)d_in[15];
    const float* c3d_b  = (const float*)d_in[16];
    float* out = (float*)d_out;

    // workspace carve-up (~87 MB)
    unsigned short* XpA    = (unsigned short*)d_ws;          // 2,959,360 us
    unsigned short* XpB    = XpA + (size_t)XP_ROWS * 256;    // 2,959,360 us (adjacent for zero_k)
    unsigned short* wtoff  = XpB + (size_t)XP_ROWS * 256;    // 4*128*6912
    unsigned short* wtmain = wtoff + (size_t)4 * 128 * KTOT; // 4*256*6912
    float* dbufp = (float*)(wtmain + (size_t)4 * 256 * KTOT);// 108*8192 fp32
    float* parts = dbufp + (size_t)108 * NPOS;               // KS*256*8192 fp32

    const dim3 blk(256);
    const dim3 gG(128, KS);

    zero_k<<<2890, blk, 0, stream>>>(XpA);                   // zeros XpA + XpB
    pad_x_t<<<256, blk, 0, stream>>>(x, XpA);
    wtrans_all<<<1536, blk, 0, stream>>>(ow1, ow2, ow3, defo_w, w1, w2, w3, c3d_w, wtoff, wtmain);

    const float* cbias[4] = {ob1, ob2, ob3, defo_b};
    const float* dbias[4] = {b1, b2, b3, c3d_b};

    for (int L = 0; L < 4; ++L) {
        const unsigned short* featConv = (L == 0) ? XpA : XpB;          // conv input = h_{L-1}
        const unsigned short* featDef  = (L == 3) ? XpA : featConv;     // final deform samples original x
        fgemm<false><<<gG, blk, 0, stream>>>(featConv, wtoff + (size_t)L * 128 * KTOT, nullptr, parts);
        ccombine<<<864, blk, 0, stream>>>(parts, cbias[L], dbufp);
        fgemm<true><<<gG, blk, 0, stream>>>(featDef, wtmain + (size_t)L * 256 * KTOT, dbufp, parts);
        if (L < 3) dcombine_h<<<dim3(128, 4), blk, 0, stream>>>(parts, dbias[L], XpB);
        else       dcombine_out<<<2048, blk, 0, stream>>>(parts, dbias[L], out);
    }
}

// Round 6
// 766.572 us; speedup vs baseline: 1.2133x; 1.1335x over previous
//
#include <hip/hip_runtime.h>
#include <cstdint>

// ---------------- problem constants ----------------
#define NPOS 8192              // 8*32*32 spatial positions
#define KTOT 6912              // 27 taps * 256 channels
#define XP_ROWS 11560          // 10*34*34 padded spatial rows
#define XP_SY 34
#define XP_SZ 1156             // 34*34
#define KS 4                   // K-splits (R5: back to 4 — KS=6 regressed; see journal)
#define KSL 1728               // KTOT/KS
#define NCHUNK 27              // KSL/64

typedef float  facc_t __attribute__((ext_vector_type(4)));
typedef short  bf8_t  __attribute__((ext_vector_type(8)));   // MFMA bf16 frag (4 VGPRs)
typedef unsigned short ub8_t __attribute__((ext_vector_type(8)));

__device__ __forceinline__ unsigned short f2bf(float f) {
    unsigned u = __float_as_uint(f);
    u = (u + 0x7FFFu + ((u >> 16) & 1u)) >> 16;   // RNE
    return (unsigned short)u;
}
__device__ __forceinline__ float bf2f(unsigned short u) {
    return __uint_as_float(((unsigned)u) << 16);
}

// ---------------- zero XpA+XpB (adjacent, 2*2,959,360 us) ----------------
__global__ __launch_bounds__(256) void zero_k(unsigned short* __restrict__ dst) {
    ub8_t zz = {0,0,0,0,0,0,0,0};
    *(ub8_t*)&dst[((size_t)blockIdx.x * 256 + threadIdx.x) * 8] = zz;
}

// ---------------- pad x: fp32 c-major (256,8192) -> interior of XpA[row][256] bf16 ----------------
// grid 256 = (z*32+y); LDS transpose so both sides are coalesced
__global__ __launch_bounds__(256) void pad_x_t(const float* __restrict__ x,
                                               unsigned short* __restrict__ XpA) {
    __shared__ unsigned short T[256 * 33];
    int b = blockIdx.x;
    int z = b >> 5, y = b & 31;
    int t = threadIdx.x;
    int c8 = t >> 5, xv = t & 31;
#pragma unroll 4
    for (int i = 0; i < 32; ++i) {
        int c = i * 8 + c8;
        T[c * 33 + xv] = f2bf(x[c * NPOS + (z << 10) + (y << 5) + xv]);
    }
    __syncthreads();
    int rowb = ((z + 1) * XP_SZ + (y + 1) * XP_SY + 1) * 256;
#pragma unroll 4
    for (int j = 0; j < 32; ++j) {
        XpA[rowb + j * 256 + t] = T[t * 33 + j];
    }
}

// ---------------- all 8 weight transposes in one launch ----------------
// src w[o][c][k] fp32 (row = 6912 contiguous) -> dst[o][k*256+c] bf16
__global__ __launch_bounds__(256) void wtrans_all(
    const float* __restrict__ o1, const float* __restrict__ o2,
    const float* __restrict__ o3, const float* __restrict__ o4,
    const float* __restrict__ m1, const float* __restrict__ m2,
    const float* __restrict__ m3, const float* __restrict__ m4,
    unsigned short* __restrict__ wtoff, unsigned short* __restrict__ wtmain) {
    __shared__ float T[6912];
    int b = blockIdx.x, t = threadIdx.x;
    const float* src; unsigned short* dst; int o, O;
    if (b < 512) {
        int L = b >> 7; o = b & 127; O = 108;
        src = (L == 0) ? o1 : (L == 1) ? o2 : (L == 2) ? o3 : o4;
        dst = wtoff + ((size_t)(L * 128 + o)) * KTOT;
    } else {
        int b2 = b - 512;
        int L = b2 >> 8; o = b2 & 255; O = 256;
        src = (L == 0) ? m1 : (L == 1) ? m2 : (L == 2) ? m3 : m4;
        dst = wtmain + ((size_t)(L * 256 + o)) * KTOT;
    }
    if (o < O) {
#pragma unroll 3
        for (int i = 0; i < 27; ++i) T[i * 256 + t] = src[(size_t)o * KTOT + i * 256 + t];
        __syncthreads();
#pragma unroll 3
        for (int i = 0; i < 27; ++i) {
            int kc = i * 256 + t;
            int c = kc & 255, k = kc >> 8;
            dst[kc] = f2bf(T[c * 27 + k]);
        }
    } else {
#pragma unroll 3
        for (int i = 0; i < 27; ++i) dst[i * 256 + t] = 0;
    }
}

// ---------------- fused implicit GEMM (conv or deformable), K-split partials ----------------
// parts[ks][O][8192] += A[o][kc]*B[p][kc] over kc in [ks*KSL, +KSL)
// DEFORM: B staged per chunk by on-the-fly trilinear sampling from Xp (bf16 pos-major, padded)
// CONV:   B staged by integer-tap row copy from Xp
// R5: XCD-chunked block swizzle (T1). Linear bid round-robins XCDs (bid&7);
// give XCD x the CONTIGUOUS p-tiles [x*16, x*16+16) (= one full z-slab, 1024
// positions) x all KS splits. Per-XCD gather footprint = z-slab +-2 ~ 2.4 MB
// + wt slice < 4 MiB L2 -> trilinear gathers become L2 hits instead of HBM
// thrash (R4 FETCH showed Xp re-fetched 4-6x from HBM).
// Bijective for 512 = 8 XCD x 16 pt x 4 ks. Perf-only; correctness unaffected.
template<bool DEFORM>
__global__ __launch_bounds__(256)
void fgemm(const unsigned short* __restrict__ Xp,
           const unsigned short* __restrict__ wt,   // [O][KTOT] bf16
           const float* __restrict__ dbuf,          // [108][8192] (DEFORM only)
           float* __restrict__ parts) {
    constexpr int O   = DEFORM ? 256 : 128;
    constexpr int PWN = DEFORM ? 4 : 2;             // p-frags per wave
    __shared__ unsigned short Bs[64 * 64] __attribute__((aligned(16)));

    const int t = threadIdx.x;
    const int wave = t >> 6, lane = t & 63;
    const int q = lane >> 4, r = lane & 15;

    // ---- XCD-chunked swizzle (requires grid = (128, 4), 512 blocks) ----
    const int bid = blockIdx.x + (blockIdx.y << 7);  // linear id, x fastest
    const int xcd = bid & 7;
    const int idx = bid >> 3;                        // 0..63 within XCD
    const int pt  = (xcd << 4) | (idx & 15);         // 16 contiguous p-tiles/XCD
    const int ks  = idx >> 4;                        // 0..3
    const int pbase = pt * 64;
    const int kstart = ks * KSL;

    const int obw = DEFORM ? (wave * 64) : ((wave >> 1) * 64);
    const int pfb = DEFORM ? 0 : ((wave & 1) * 32);

    // staging coords: thread -> (p_local = t>>2, 16 channels at csub)
    const int pl = t >> 2;
    const int csub = (t & 3) * 16;
    const int p = pbase + pl;
    const int z = p >> 10, y = (p >> 5) & 31, xx = p & 31;
    const int g0 = (t & 3) * 2;
    const int wr0 = pl * 64 + ((g0 ^ (pl & 7)) << 3);
    const int wr1 = pl * 64 + (((g0 + 1) ^ (pl & 7)) << 3);

    facc_t acc[4][PWN];
#pragma unroll
    for (int i = 0; i < 4; ++i)
#pragma unroll
        for (int ip = 0; ip < PWN; ++ip) acc[i][ip] = (facc_t){0.f, 0.f, 0.f, 0.f};

    float cw[8];
    int row0 = 0;
    int kprev = -1;

    for (int chunk = 0; chunk < NCHUNK; ++chunk) {
        const int kc0 = kstart + chunk * 64;
        const int k = kc0 >> 8;
        const int c0 = kc0 & 255;
        const int kd = k / 9, kh = (k / 3) % 3, kw = k % 3;

        // ---- A-fragments straight from global (L2-resident weights) ----
        bf8_t afr[2][4];
#pragma unroll
        for (int sl = 0; sl < 2; ++sl)
#pragma unroll
            for (int i = 0; i < 4; ++i)
                afr[sl][i] = *(const bf8_t*)&wt[(size_t)(obw + i * 16 + r) * KTOT + kc0 + sl * 32 + q * 8];

        // ---- B staging ----
        if (DEFORM) {
            if (k != kprev) {
                kprev = k;
                float od  = dbuf[(3 * k + 0) * NPOS + p];
                float oh  = dbuf[(3 * k + 1) * NPOS + p];
                float ow_ = dbuf[(3 * k + 2) * NPOS + p];
                float m   = dbuf[(81 + k) * NPOS + p];
                float cd = (float)(z + kd - 1) + od;
                float ch = (float)(y + kh - 1) + oh;
                float cx = (float)(xx + kw - 1) + ow_;
                float fdf = floorf(cd), fhf = floorf(ch), fwf = floorf(cx);
                float fd = cd - fdf, fh = ch - fhf, fw = cx - fwf;
                float wz0 = 1.f - fd, wz1 = fd;
                float wy0 = 1.f - fh, wy1 = fh;
                float wx0 = 1.f - fw, wx1 = fw;
                int id, ih, iw;
                if (fdf < -1.f || fdf >= 8.f)  { wz0 = 0.f; wz1 = 0.f; id = 0; } else id = (int)fdf;
                if (fhf < -1.f || fhf >= 32.f) { wy0 = 0.f; wy1 = 0.f; ih = 0; } else ih = (int)fhf;
                if (fwf < -1.f || fwf >= 32.f) { wx0 = 0.f; wx1 = 0.f; iw = 0; } else iw = (int)fwf;
                wz0 *= m; wz1 *= m;
                float w00 = wz0 * wy0, w01 = wz0 * wy1, w10 = wz1 * wy0, w11 = wz1 * wy1;
                cw[0] = w00 * wx0; cw[1] = w00 * wx1;
                cw[2] = w01 * wx0; cw[3] = w01 * wx1;
                cw[4] = w10 * wx0; cw[5] = w10 * wx1;
                cw[6] = w11 * wx0; cw[7] = w11 * wx1;
                row0 = (id + 1) * XP_SZ + (ih + 1) * XP_SY + (iw + 1);
            }
            float av[16];
#pragma unroll
            for (int e = 0; e < 16; ++e) av[e] = 0.f;
            const unsigned short* cb = Xp + (size_t)row0 * 256 + c0 + csub;
#pragma unroll
            for (int j = 0; j < 8; ++j) {
                const int roff = ((j >> 2) & 1) * XP_SZ + ((j >> 1) & 1) * XP_SY + (j & 1);
                ub8_t lo = *(const ub8_t*)(cb + roff * 256);
                ub8_t hi = *(const ub8_t*)(cb + roff * 256 + 8);
#pragma unroll
                for (int e = 0; e < 8; ++e) {
                    av[e]     += cw[j] * bf2f(lo[e]);
                    av[8 + e] += cw[j] * bf2f(hi[e]);
                }
            }
            ub8_t v0, v1;
#pragma unroll
            for (int e = 0; e < 8; ++e) { v0[e] = f2bf(av[e]); v1[e] = f2bf(av[8 + e]); }
            *(ub8_t*)&Bs[wr0] = v0;
            *(ub8_t*)&Bs[wr1] = v1;
        } else {
            int row = (z + kd) * XP_SZ + (y + kh) * XP_SY + (xx + kw);
            ub8_t lo = *(const ub8_t*)&Xp[(size_t)row * 256 + c0 + csub];
            ub8_t hi = *(const ub8_t*)&Xp[(size_t)row * 256 + c0 + csub + 8];
            *(ub8_t*)&Bs[wr0] = lo;
            *(ub8_t*)&Bs[wr1] = hi;
        }
        __syncthreads();

        // ---- MFMA ----
#pragma unroll
        for (int sl = 0; sl < 2; ++sl) {
            bf8_t bfr[PWN];
#pragma unroll
            for (int ip = 0; ip < PWN; ++ip) {
                int brow = pfb + ip * 16 + r;
                bfr[ip] = *(const bf8_t*)&Bs[brow * 64 + (((sl * 4 + q) ^ (brow & 7)) << 3)];
            }
#pragma unroll
            for (int i = 0; i < 4; ++i)
#pragma unroll
                for (int ip = 0; ip < PWN; ++ip)
                    acc[i][ip] = __builtin_amdgcn_mfma_f32_16x16x32_bf16(afr[sl][i], bfr[ip], acc[i][ip], 0, 0, 0);
        }
        __syncthreads();
    }

    // ---- epilogue: fp32 partials; C/D map row(o)=q*4+reg, col(p)=r [R1/R2-verified] ----
    float* pp = parts + (size_t)ks * O * NPOS;
#pragma unroll
    for (int i = 0; i < 4; ++i)
#pragma unroll
        for (int ip = 0; ip < PWN; ++ip)
#pragma unroll
            for (int reg = 0; reg < 4; ++reg) {
                int o = obw + i * 16 + q * 4 + reg;
                int px = pbase + pfb + ip * 16 + r;
                pp[(size_t)o * NPOS + px] = acc[i][ip][reg];
            }
}

// ---------------- combine conv partials -> dbuf (bias + sigmoid on o>=81) ----------------
__global__ __launch_bounds__(256) void ccombine(const float* __restrict__ parts,
                                                const float* __restrict__ ob,
                                                float* __restrict__ dbuf) {
    int b = blockIdx.x;                 // 108*8
    int o = b >> 3;
    int p4 = ((b & 7) * 256 + threadIdx.x) * 4;
    float s0 = 0, s1 = 0, s2 = 0, s3 = 0;
#pragma unroll
    for (int s = 0; s < KS; ++s) {
        const float4 v = *(const float4*)&parts[((size_t)(s * 128 + o)) * NPOS + p4];
        s0 += v.x; s1 += v.y; s2 += v.z; s3 += v.w;
    }
    float bv = ob[o];
    s0 += bv; s1 += bv; s2 += bv; s3 += bv;
    if (o >= 81) {
        s0 = 1.f / (1.f + __expf(-s0));
        s1 = 1.f / (1.f + __expf(-s1));
        s2 = 1.f / (1.f + __expf(-s2));
        s3 = 1.f / (1.f + __expf(-s3));
    }
    *(float4*)&dbuf[(size_t)o * NPOS + p4] = make_float4(s0, s1, s2, s3);
}

// ---------------- combine deform partials -> relu bf16, transposed into XpB interior ----------------
// grid (128 p-tiles, 4 o-tiles)
__global__ __launch_bounds__(256) void dcombine_h(const float* __restrict__ parts,
                                                  const float* __restrict__ bias,
                                                  unsigned short* __restrict__ XpB) {
    __shared__ unsigned short T[64 * 66];
    int p0 = blockIdx.x * 64, o0 = blockIdx.y * 64;
    int t = threadIdx.x;
    int pl = t & 63, og = t >> 6;
#pragma unroll 4
    for (int j = 0; j < 16; ++j) {
        int ol = og * 16 + j;
        float s = 0.f;
#pragma unroll
        for (int sp = 0; sp < KS; ++sp)
            s += parts[((size_t)(sp * 256 + o0 + ol)) * NPOS + p0 + pl];
        s += bias[o0 + ol];
        T[ol * 66 + pl] = f2bf(fmaxf(s, 0.f));
    }
    __syncthreads();
    int c = t & 63, pr = t >> 6;
#pragma unroll 4
    for (int j = 0; j < 16; ++j) {
        int pl2 = j * 4 + pr;
        int pg = p0 + pl2;
        int zz = pg >> 10, yy = (pg >> 5) & 31, xv = pg & 31;
        int row = (zz + 1) * XP_SZ + (yy + 1) * XP_SY + xv + 1;
        XpB[(size_t)row * 256 + o0 + c] = T[c * 66 + pl2];
    }
}

// ---------------- final combine -> fp32 o-major output (bias only) ----------------
__global__ __launch_bounds__(256) void dcombine_out(const float* __restrict__ parts,
                                                    const float* __restrict__ bias,
                                                    float* __restrict__ out) {
    int b = blockIdx.x;                 // 256*8
    int o = b >> 3;
    int p4 = ((b & 7) * 256 + threadIdx.x) * 4;
    float s0 = 0, s1 = 0, s2 = 0, s3 = 0;
#pragma unroll
    for (int s = 0; s < KS; ++s) {
        const float4 v = *(const float4*)&parts[((size_t)(s * 256 + o)) * NPOS + p4];
        s0 += v.x; s1 += v.y; s2 += v.z; s3 += v.w;
    }
    float bv = bias[o];
    *(float4*)&out[(size_t)o * NPOS + p4] = make_float4(s0 + bv, s1 + bv, s2 + bv, s3 + bv);
}

// ---------------- host orchestration ----------------
extern "C" void kernel_launch(void* const* d_in, const int* in_sizes, int n_in,
                              void* d_out, int out_size, void* d_ws, size_t ws_size,
                              hipStream_t stream) {
    const float* x      = (const float*)d_in[0];
    const float* ow1    = (const float*)d_in[1];
    const float* ob1    = (const float*)d_in[2];
    const float* w1     = (const float*)d_in[3];
    const float* b1     = (const float*)d_in[4];
    const float* ow2    = (const float*)d_in[5];
    const float* ob2    = (const float*)d_in[6];
    const float* w2     = (const float*)d_in[7];
    const float* b2     = (const float*)d_in[8];
    const float* ow3    = (const float*)d_in[9];
    const float* ob3    = (const float*)d_in[10];
    const float* w3     = (const float*)d_in[11];
    const float* b3     = (const float*)d_in[12];
    const float* defo_w = (const float*)d_in[13];
    const float* defo_b = (const float*)d_in[14];
    const float* c3d_w  = (const float*)d_in[15];
    const float* c3d_b  = (const float*)d_in[16];
    float* out = (float*)d_out;

    // workspace carve-up (~70 MB)
    unsigned short* XpA    = (unsigned short*)d_ws;          // 2,959,360 us
    unsigned short* XpB    = XpA + (size_t)XP_ROWS * 256;    // 2,959,360 us (adjacent for zero_k)
    unsigned short* wtoff  = XpB + (size_t)XP_ROWS * 256;    // 4*128*6912
    unsigned short* wtmain = wtoff + (size_t)4 * 128 * KTOT; // 4*256*6912
    float* dbufp = (float*)(wtmain + (size_t)4 * 256 * KTOT);// 108*8192 fp32
    float* parts = dbufp + (size_t)108 * NPOS;               // KS*256*8192 fp32

    const dim3 blk(256);
    const dim3 gG(128, KS);

    zero_k<<<2890, blk, 0, stream>>>(XpA);                   // zeros XpA + XpB
    pad_x_t<<<256, blk, 0, stream>>>(x, XpA);
    wtrans_all<<<1536, blk, 0, stream>>>(ow1, ow2, ow3, defo_w, w1, w2, w3, c3d_w, wtoff, wtmain);

    const float* cbias[4] = {ob1, ob2, ob3, defo_b};
    const float* dbias[4] = {b1, b2, b3, c3d_b};

    for (int L = 0; L < 4; ++L) {
        const unsigned short* featConv = (L == 0) ? XpA : XpB;          // conv input = h_{L-1}
        const unsigned short* featDef  = (L == 3) ? XpA : featConv;     // final deform samples original x
        fgemm<false><<<gG, blk, 0, stream>>>(featConv, wtoff + (size_t)L * 128 * KTOT, nullptr, parts);
        ccombine<<<864, blk, 0, stream>>>(parts, cbias[L], dbufp);
        fgemm<true><<<gG, blk, 0, stream>>>(featDef, wtmain + (size_t)L * 256 * KTOT, dbufp, parts);
        if (L < 3) dcombine_h<<<dim3(128, 4), blk, 0, stream>>>(parts, dbias[L], XpB);
        else       dcombine_out<<<2048, blk, 0, stream>>>(parts, dbias[L], out);
    }
}

// Round 8
// 742.221 us; speedup vs baseline: 1.2531x; 1.0328x over previous
//
#include <hip/hip_runtime.h>
#include <cstdint>

// ---------------- problem constants ----------------
#define NPOS 8192              // 8*32*32 spatial positions
#define KTOT 6912              // 27 taps * 256 channels
#define XP_ROWS 11560          // 10*34*34 padded spatial rows
#define XP_SY 34
#define XP_SZ 1156             // 34*34
#define KS 4                   // K-splits
#define KSL 1728               // KTOT/KS
#define NCHUNK 27              // KSL/64

typedef float  facc_t __attribute__((ext_vector_type(4)));
typedef short  bf8_t  __attribute__((ext_vector_type(8)));   // MFMA bf16 frag (4 VGPRs)
typedef unsigned short ub8_t __attribute__((ext_vector_type(8)));

__device__ __forceinline__ unsigned short f2bf(float f) {
    unsigned u = __float_as_uint(f);
    u = (u + 0x7FFFu + ((u >> 16) & 1u)) >> 16;   // RNE
    return (unsigned short)u;
}
__device__ __forceinline__ float bf2f(unsigned short u) {
    return __uint_as_float(((unsigned)u) << 16);
}

// ---------------- zero XpA+XpB (adjacent, 2*2,959,360 us) ----------------
__global__ __launch_bounds__(256) void zero_k(unsigned short* __restrict__ dst) {
    ub8_t zz = {0,0,0,0,0,0,0,0};
    *(ub8_t*)&dst[((size_t)blockIdx.x * 256 + threadIdx.x) * 8] = zz;
}

// ---------------- pad x: fp32 c-major (256,8192) -> interior of XpA[row][256] bf16 ----------------
__global__ __launch_bounds__(256) void pad_x_t(const float* __restrict__ x,
                                               unsigned short* __restrict__ XpA) {
    __shared__ unsigned short T[256 * 33];
    int b = blockIdx.x;
    int z = b >> 5, y = b & 31;
    int t = threadIdx.x;
    int c8 = t >> 5, xv = t & 31;
#pragma unroll 4
    for (int i = 0; i < 32; ++i) {
        int c = i * 8 + c8;
        T[c * 33 + xv] = f2bf(x[c * NPOS + (z << 10) + (y << 5) + xv]);
    }
    __syncthreads();
    int rowb = ((z + 1) * XP_SZ + (y + 1) * XP_SY + 1) * 256;
#pragma unroll 4
    for (int j = 0; j < 32; ++j) {
        XpA[rowb + j * 256 + t] = T[t * 33 + j];
    }
}

// ---------------- all 8 weight transposes in one launch ----------------
__global__ __launch_bounds__(256) void wtrans_all(
    const float* __restrict__ o1, const float* __restrict__ o2,
    const float* __restrict__ o3, const float* __restrict__ o4,
    const float* __restrict__ m1, const float* __restrict__ m2,
    const float* __restrict__ m3, const float* __restrict__ m4,
    unsigned short* __restrict__ wtoff, unsigned short* __restrict__ wtmain) {
    __shared__ float T[6912];
    int b = blockIdx.x, t = threadIdx.x;
    const float* src; unsigned short* dst; int o, O;
    if (b < 512) {
        int L = b >> 7; o = b & 127; O = 108;
        src = (L == 0) ? o1 : (L == 1) ? o2 : (L == 2) ? o3 : o4;
        dst = wtoff + ((size_t)(L * 128 + o)) * KTOT;
    } else {
        int b2 = b - 512;
        int L = b2 >> 8; o = b2 & 255; O = 256;
        src = (L == 0) ? m1 : (L == 1) ? m2 : (L == 2) ? m3 : m4;
        dst = wtmain + ((size_t)(L * 256 + o)) * KTOT;
    }
    if (o < O) {
#pragma unroll 3
        for (int i = 0; i < 27; ++i) T[i * 256 + t] = src[(size_t)o * KTOT + i * 256 + t];
        __syncthreads();
#pragma unroll 3
        for (int i = 0; i < 27; ++i) {
            int kc = i * 256 + t;
            int c = kc & 255, k = kc >> 8;
            dst[kc] = f2bf(T[c * 27 + k]);
        }
    } else {
#pragma unroll 3
        for (int i = 0; i < 27; ++i) dst[i * 256 + t] = 0;
    }
}

// ---------------- fused implicit GEMM (conv or deformable), K-split partials ----------------
// R6 (T4): raw s_barrier instead of __syncthreads -> vmcnt NEVER drained at
// barriers (the implicit vmcnt(0) drain was killing every in-flight load twice
// per chunk). Deform gathers software-pipelined one chunk ahead: chunk c+1's
// 16 register-target loads (+ per-tap dbuf/weights) issue right after blend c
// consumes the registers; their latency hides under write+barrier+MFMA of c.
// Register loads carry no cross-wave hazard, so they legally span barriers.
// ds_write visibility: lgkmcnt(0) before the pre-MFMA barrier (m201 template);
// sched_barrier(0) after each barrier pins load/ds motion (rule #18).
template<bool DEFORM>
__global__ __launch_bounds__(256, 2)
void fgemm(const unsigned short* __restrict__ Xp,
           const unsigned short* __restrict__ wt,   // [O][KTOT] bf16
           const float* __restrict__ dbuf,          // [108][8192] (DEFORM only)
           float* __restrict__ parts) {
    constexpr int O   = DEFORM ? 256 : 128;
    constexpr int PWN = DEFORM ? 4 : 2;             // p-frags per wave
    __shared__ unsigned short Bs[64 * 64] __attribute__((aligned(16)));

    const int t = threadIdx.x;
    const int wave = t >> 6, lane = t & 63;
    const int q = lane >> 4, r = lane & 15;

    // ---- XCD-chunked swizzle (neutral R5; kept — mechanically sound, grid (128,4)) ----
    const int bid = blockIdx.x + (blockIdx.y << 7);
    const int xcd = bid & 7;
    const int idx = bid >> 3;
    const int pt  = (xcd << 4) | (idx & 15);
    const int ks  = idx >> 4;
    const int pbase = pt * 64;
    const int kstart = ks * KSL;

    const int obw = DEFORM ? (wave * 64) : ((wave >> 1) * 64);
    const int pfb = DEFORM ? 0 : ((wave & 1) * 32);

    // staging coords: thread -> (p_local = t>>2, 16 channels at csub)
    const int pl = t >> 2;
    const int csub = (t & 3) * 16;
    const int p = pbase + pl;
    const int z = p >> 10, y = (p >> 5) & 31, xx = p & 31;
    const int g0 = (t & 3) * 2;
    const int wr0 = pl * 64 + ((g0 ^ (pl & 7)) << 3);
    const int wr1 = pl * 64 + (((g0 + 1) ^ (pl & 7)) << 3);

    facc_t acc[4][PWN];
#pragma unroll
    for (int i = 0; i < 4; ++i)
#pragma unroll
        for (int ip = 0; ip < PWN; ++ip) acc[i][ip] = (facc_t){0.f, 0.f, 0.f, 0.f};

    float cw[8];
    int row0 = 0;
    int kprev = -1;
    ub8_t stv[16];                                  // in-flight gather registers

    // prep weights for tap of kc0_s (if new) and issue the 16 gathers for that chunk
    auto prep_issue = [&](int kc0_s) {
        const int k_s = kc0_s >> 8;
        const int c0_s = kc0_s & 255;
        if (k_s != kprev) {
            kprev = k_s;
            const int kd = k_s / 9, kh = (k_s / 3) % 3, kw = k_s % 3;
            float od  = dbuf[(3 * k_s + 0) * NPOS + p];
            float oh  = dbuf[(3 * k_s + 1) * NPOS + p];
            float ow_ = dbuf[(3 * k_s + 2) * NPOS + p];
            float m   = dbuf[(81 + k_s) * NPOS + p];
            float cd = (float)(z + kd - 1) + od;
            float ch = (float)(y + kh - 1) + oh;
            float cx = (float)(xx + kw - 1) + ow_;
            float fdf = floorf(cd), fhf = floorf(ch), fwf = floorf(cx);
            float fd = cd - fdf, fh = ch - fhf, fw = cx - fwf;
            float wz0 = 1.f - fd, wz1 = fd;
            float wy0 = 1.f - fh, wy1 = fh;
            float wx0 = 1.f - fw, wx1 = fw;
            int id, ih, iw;
            if (fdf < -1.f || fdf >= 8.f)  { wz0 = 0.f; wz1 = 0.f; id = 0; } else id = (int)fdf;
            if (fhf < -1.f || fhf >= 32.f) { wy0 = 0.f; wy1 = 0.f; ih = 0; } else ih = (int)fhf;
            if (fwf < -1.f || fwf >= 32.f) { wx0 = 0.f; wx1 = 0.f; iw = 0; } else iw = (int)fwf;
            wz0 *= m; wz1 *= m;
            float w00 = wz0 * wy0, w01 = wz0 * wy1, w10 = wz1 * wy0, w11 = wz1 * wy1;
            cw[0] = w00 * wx0; cw[1] = w00 * wx1;
            cw[2] = w01 * wx0; cw[3] = w01 * wx1;
            cw[4] = w10 * wx0; cw[5] = w10 * wx1;
            cw[6] = w11 * wx0; cw[7] = w11 * wx1;
            row0 = (id + 1) * XP_SZ + (ih + 1) * XP_SY + (iw + 1);
        }
        const unsigned short* cb = Xp + (size_t)row0 * 256 + c0_s + csub;
#pragma unroll
        for (int j = 0; j < 8; ++j) {
            const int roff = ((j >> 2) & 1) * XP_SZ + ((j >> 1) & 1) * XP_SY + (j & 1);
            stv[2 * j]     = *(const ub8_t*)(cb + roff * 256);
            stv[2 * j + 1] = *(const ub8_t*)(cb + roff * 256 + 8);
        }
    };

    if (DEFORM) prep_issue(kstart);                 // chunk 0 gathers in flight

    for (int chunk = 0; chunk < NCHUNK; ++chunk) {
        const int kc0 = kstart + chunk * 64;
        const int k = kc0 >> 8;
        const int c0 = kc0 & 255;
        const int kd = k / 9, kh = (k / 3) % 3, kw = k % 3;

        // ---- A-fragments (L2-resident weights); issued before blend so their
        //      latency overlaps the blend VALU ----
        bf8_t afr[2][4];
#pragma unroll
        for (int sl = 0; sl < 2; ++sl)
#pragma unroll
            for (int i = 0; i < 4; ++i)
                afr[sl][i] = *(const bf8_t*)&wt[(size_t)(obw + i * 16 + r) * KTOT + kc0 + sl * 32 + q * 8];

        // ---- B staging ----
        if (DEFORM) {
            // blend chunk's gathers (compiler inserts the precise vmcnt wait)
            float av[16];
#pragma unroll
            for (int e = 0; e < 16; ++e) av[e] = 0.f;
#pragma unroll
            for (int j = 0; j < 8; ++j) {
#pragma unroll
                for (int e = 0; e < 8; ++e) {
                    av[e]     += cw[j] * bf2f(stv[2 * j][e]);
                    av[8 + e] += cw[j] * bf2f(stv[2 * j + 1][e]);
                }
            }
            ub8_t v0, v1;
#pragma unroll
            for (int e = 0; e < 8; ++e) { v0[e] = f2bf(av[e]); v1[e] = f2bf(av[8 + e]); }
            // issue next chunk's gathers NOW: they stay in flight across the
            // barriers (registers, no cross-wave hazard) and land during MFMA
            if (chunk + 1 < NCHUNK) prep_issue(kc0 + 64);
            *(ub8_t*)&Bs[wr0] = v0;
            *(ub8_t*)&Bs[wr1] = v1;
        } else {
            int row = (z + kd) * XP_SZ + (y + kh) * XP_SY + (xx + kw);
            ub8_t lo = *(const ub8_t*)&Xp[(size_t)row * 256 + c0 + csub];
            ub8_t hi = *(const ub8_t*)&Xp[(size_t)row * 256 + c0 + csub + 8];
            *(ub8_t*)&Bs[wr0] = lo;
            *(ub8_t*)&Bs[wr1] = hi;
        }

        // ---- barrier WITHOUT vmcnt drain: ds_writes committed, loads stay in flight ----
        asm volatile("s_waitcnt lgkmcnt(0)" ::: "memory");
        __builtin_amdgcn_s_barrier();
        __builtin_amdgcn_sched_barrier(0);

        // ---- MFMA ----
#pragma unroll
        for (int sl = 0; sl < 2; ++sl) {
            bf8_t bfr[PWN];
#pragma unroll
            for (int ip = 0; ip < PWN; ++ip) {
                int brow = pfb + ip * 16 + r;
                bfr[ip] = *(const bf8_t*)&Bs[brow * 64 + (((sl * 4 + q) ^ (brow & 7)) << 3)];
            }
#pragma unroll
            for (int i = 0; i < 4; ++i)
#pragma unroll
                for (int ip = 0; ip < PWN; ++ip)
                    acc[i][ip] = __builtin_amdgcn_mfma_f32_16x16x32_bf16(afr[sl][i], bfr[ip], acc[i][ip], 0, 0, 0);
        }

        __builtin_amdgcn_s_barrier();
        __builtin_amdgcn_sched_barrier(0);
    }

    // ---- epilogue: fp32 partials; C/D map row(o)=q*4+reg, col(p)=r [R1/R2-verified] ----
    float* pp = parts + (size_t)ks * O * NPOS;
#pragma unroll
    for (int i = 0; i < 4; ++i)
#pragma unroll
        for (int ip = 0; ip < PWN; ++ip)
#pragma unroll
            for (int reg = 0; reg < 4; ++reg) {
                int o = obw + i * 16 + q * 4 + reg;
                int px = pbase + pfb + ip * 16 + r;
                pp[(size_t)o * NPOS + px] = acc[i][ip][reg];
            }
}

// ---------------- combine conv partials -> dbuf (bias + sigmoid on o>=81) ----------------
__global__ __launch_bounds__(256) void ccombine(const float* __restrict__ parts,
                                                const float* __restrict__ ob,
                                                float* __restrict__ dbuf) {
    int b = blockIdx.x;                 // 108*8
    int o = b >> 3;
    int p4 = ((b & 7) * 256 + threadIdx.x) * 4;
    float s0 = 0, s1 = 0, s2 = 0, s3 = 0;
#pragma unroll
    for (int s = 0; s < KS; ++s) {
        const float4 v = *(const float4*)&parts[((size_t)(s * 128 + o)) * NPOS + p4];
        s0 += v.x; s1 += v.y; s2 += v.z; s3 += v.w;
    }
    float bv = ob[o];
    s0 += bv; s1 += bv; s2 += bv; s3 += bv;
    if (o >= 81) {
        s0 = 1.f / (1.f + __expf(-s0));
        s1 = 1.f / (1.f + __expf(-s1));
        s2 = 1.f / (1.f + __expf(-s2));
        s3 = 1.f / (1.f + __expf(-s3));
    }
    *(float4*)&dbuf[(size_t)o * NPOS + p4] = make_float4(s0, s1, s2, s3);
}

// ---------------- combine deform partials -> relu bf16, transposed into XpB interior ----------------
__global__ __launch_bounds__(256) void dcombine_h(const float* __restrict__ parts,
                                                  const float* __restrict__ bias,
                                                  unsigned short* __restrict__ XpB) {
    __shared__ unsigned short T[64 * 66];
    int p0 = blockIdx.x * 64, o0 = blockIdx.y * 64;
    int t = threadIdx.x;
    int pl = t & 63, og = t >> 6;
#pragma unroll 4
    for (int j = 0; j < 16; ++j) {
        int ol = og * 16 + j;
        float s = 0.f;
#pragma unroll
        for (int sp = 0; sp < KS; ++sp)
            s += parts[((size_t)(sp * 256 + o0 + ol)) * NPOS + p0 + pl];
        s += bias[o0 + ol];
        T[ol * 66 + pl] = f2bf(fmaxf(s, 0.f));
    }
    __syncthreads();
    int c = t & 63, pr = t >> 6;
#pragma unroll 4
    for (int j = 0; j < 16; ++j) {
        int pl2 = j * 4 + pr;
        int pg = p0 + pl2;
        int zz = pg >> 10, yy = (pg >> 5) & 31, xv = pg & 31;
        int row = (zz + 1) * XP_SZ + (yy + 1) * XP_SY + xv + 1;
        XpB[(size_t)row * 256 + o0 + c] = T[c * 66 + pl2];
    }
}

// ---------------- final combine -> fp32 o-major output (bias only) ----------------
__global__ __launch_bounds__(256) void dcombine_out(const float* __restrict__ parts,
                                                    const float* __restrict__ bias,
                                                    float* __restrict__ out) {
    int b = blockIdx.x;                 // 256*8
    int o = b >> 3;
    int p4 = ((b & 7) * 256 + threadIdx.x) * 4;
    float s0 = 0, s1 = 0, s2 = 0, s3 = 0;
#pragma unroll
    for (int s = 0; s < KS; ++s) {
        const float4 v = *(const float4*)&parts[((size_t)(s * 256 + o)) * NPOS + p4];
        s0 += v.x; s1 += v.y; s2 += v.z; s3 += v.w;
    }
    float bv = bias[o];
    *(float4*)&out[(size_t)o * NPOS + p4] = make_float4(s0 + bv, s1 + bv, s2 + bv, s3 + bv);
}

// ---------------- host orchestration ----------------
extern "C" void kernel_launch(void* const* d_in, const int* in_sizes, int n_in,
                              void* d_out, int out_size, void* d_ws, size_t ws_size,
                              hipStream_t stream) {
    const float* x      = (const float*)d_in[0];
    const float* ow1    = (const float*)d_in[1];
    const float* ob1    = (const float*)d_in[2];
    const float* w1     = (const float*)d_in[3];
    const float* b1     = (const float*)d_in[4];
    const float* ow2    = (const float*)d_in[5];
    const float* ob2    = (const float*)d_in[6];
    const float* w2     = (const float*)d_in[7];
    const float* b2     = (const float*)d_in[8];
    const float* ow3    = (const float*)d_in[9];
    const float* ob3    = (const float*)d_in[10];
    const float* w3     = (const float*)d_in[11];
    const float* b3     = (const float*)d_in[12];
    const float* defo_w = (const float*)d_in[13];
    const float* defo_b = (const float*)d_in[14];
    const float* c3d_w  = (const float*)d_in[15];
    const float* c3d_b  = (const float*)d_in[16];
    float* out = (float*)d_out;

    // workspace carve-up (~70 MB)
    unsigned short* XpA    = (unsigned short*)d_ws;          // 2,959,360 us
    unsigned short* XpB    = XpA + (size_t)XP_ROWS * 256;    // 2,959,360 us (adjacent for zero_k)
    unsigned short* wtoff  = XpB + (size_t)XP_ROWS * 256;    // 4*128*6912
    unsigned short* wtmain = wtoff + (size_t)4 * 128 * KTOT; // 4*256*6912
    float* dbufp = (float*)(wtmain + (size_t)4 * 256 * KTOT);// 108*8192 fp32
    float* parts = dbufp + (size_t)108 * NPOS;               // KS*256*8192 fp32

    const dim3 blk(256);
    const dim3 gG(128, KS);

    zero_k<<<2890, blk, 0, stream>>>(XpA);                   // zeros XpA + XpB
    pad_x_t<<<256, blk, 0, stream>>>(x, XpA);
    wtrans_all<<<1536, blk, 0, stream>>>(ow1, ow2, ow3, defo_w, w1, w2, w3, c3d_w, wtoff, wtmain);

    const float* cbias[4] = {ob1, ob2, ob3, defo_b};
    const float* dbias[4] = {b1, b2, b3, c3d_b};

    for (int L = 0; L < 4; ++L) {
        const unsigned short* featConv = (L == 0) ? XpA : XpB;          // conv input = h_{L-1}
        const unsigned short* featDef  = (L == 3) ? XpA : featConv;     // final deform samples original x
        fgemm<false><<<gG, blk, 0, stream>>>(featConv, wtoff + (size_t)L * 128 * KTOT, nullptr, parts);
        ccombine<<<864, blk, 0, stream>>>(parts, cbias[L], dbufp);
        fgemm<true><<<gG, blk, 0, stream>>>(featDef, wtmain + (size_t)L * 256 * KTOT, dbufp, parts);
        if (L < 3) dcombine_h<<<dim3(128, 4), blk, 0, stream>>>(parts, dbias[L], XpB);
        else       dcombine_out<<<2048, blk, 0, stream>>>(parts, dbias[L], out);
    }
}

// Round 12
// 738.247 us; speedup vs baseline: 1.2598x; 1.0054x over previous
//
#include <hip/hip_runtime.h>
#include <cstdint>

// ---------------- problem constants ----------------
#define NPOS 8192              // 8*32*32 spatial positions
#define KTOT 6912              // 27 taps * 256 channels
#define XP_ROWS 11560          // 10*34*34 padded spatial rows
#define XP_SY 34
#define XP_SZ 1156             // 34*34
#define KS 4                   // K-splits
#define KSL 1728               // KTOT/KS
#define NCHUNK 27              // KSL/64

typedef float  facc_t __attribute__((ext_vector_type(4)));
typedef short  bf8_t  __attribute__((ext_vector_type(8)));   // MFMA bf16 frag (4 VGPRs)
typedef unsigned short ub8_t __attribute__((ext_vector_type(8)));

__device__ __forceinline__ unsigned short f2bf(float f) {
    unsigned u = __float_as_uint(f);
    u = (u + 0x7FFFu + ((u >> 16) & 1u)) >> 16;   // RNE
    return (unsigned short)u;
}
__device__ __forceinline__ float bf2f(unsigned short u) {
    return __uint_as_float(((unsigned)u) << 16);
}

// ---------------- zero XpA+XpB (adjacent, 2*2,959,360 us) ----------------
__global__ __launch_bounds__(256) void zero_k(unsigned short* __restrict__ dst) {
    ub8_t zz = {0,0,0,0,0,0,0,0};
    *(ub8_t*)&dst[((size_t)blockIdx.x * 256 + threadIdx.x) * 8] = zz;
}

// ---------------- pad x: fp32 c-major (256,8192) -> interior of XpA[row][256] bf16 ----------------
__global__ __launch_bounds__(256) void pad_x_t(const float* __restrict__ x,
                                               unsigned short* __restrict__ XpA) {
    __shared__ unsigned short T[256 * 33];
    int b = blockIdx.x;
    int z = b >> 5, y = b & 31;
    int t = threadIdx.x;
    int c8 = t >> 5, xv = t & 31;
#pragma unroll 4
    for (int i = 0; i < 32; ++i) {
        int c = i * 8 + c8;
        T[c * 33 + xv] = f2bf(x[c * NPOS + (z << 10) + (y << 5) + xv]);
    }
    __syncthreads();
    int rowb = ((z + 1) * XP_SZ + (y + 1) * XP_SY + 1) * 256;
#pragma unroll 4
    for (int j = 0; j < 32; ++j) {
        XpA[rowb + j * 256 + t] = T[t * 33 + j];
    }
}

// ---------------- all 8 weight transposes in one launch ----------------
__global__ __launch_bounds__(256) void wtrans_all(
    const float* __restrict__ o1, const float* __restrict__ o2,
    const float* __restrict__ o3, const float* __restrict__ o4,
    const float* __restrict__ m1, const float* __restrict__ m2,
    const float* __restrict__ m3, const float* __restrict__ m4,
    unsigned short* __restrict__ wtoff, unsigned short* __restrict__ wtmain) {
    __shared__ float T[6912];
    int b = blockIdx.x, t = threadIdx.x;
    const float* src; unsigned short* dst; int o, O;
    if (b < 512) {
        int L = b >> 7; o = b & 127; O = 108;
        src = (L == 0) ? o1 : (L == 1) ? o2 : (L == 2) ? o3 : o4;
        dst = wtoff + ((size_t)(L * 128 + o)) * KTOT;
    } else {
        int b2 = b - 512;
        int L = b2 >> 8; o = b2 & 255; O = 256;
        src = (L == 0) ? m1 : (L == 1) ? m2 : (L == 2) ? m3 : m4;
        dst = wtmain + ((size_t)(L * 256 + o)) * KTOT;
    }
    if (o < O) {
#pragma unroll 3
        for (int i = 0; i < 27; ++i) T[i * 256 + t] = src[(size_t)o * KTOT + i * 256 + t];
        __syncthreads();
#pragma unroll 3
        for (int i = 0; i < 27; ++i) {
            int kc = i * 256 + t;
            int c = kc & 255, k = kc >> 8;
            dst[kc] = f2bf(T[c * 27 + k]);
        }
    } else {
#pragma unroll 3
        for (int i = 0; i < 27; ++i) dst[i * 256 + t] = 0;
    }
}

// ---------------- fused implicit GEMM (conv or deformable), K-split partials ----------------
// R6 (T4, verified +9%): raw s_barrier, vmcnt never drained; deform gathers
// pipelined one chunk ahead in registers.
// R8: (a) tap-lookahead — dbuf scalars for tap k+1 prefetched at each tap
// boundary (consumed ~4 chunks later), breaking the dbuf->addr->gather
// dependent chain that sat exposed on ~7/27 chunks; (b) conv staging pipelined
// one chunk ahead into registers (same mechanism), removing the naked
// load->ds_write latency every conv chunk.
template<bool DEFORM>
__global__ __launch_bounds__(256, 2)
void fgemm(const unsigned short* __restrict__ Xp,
           const unsigned short* __restrict__ wt,   // [O][KTOT] bf16
           const float* __restrict__ dbuf,          // [108][8192] (DEFORM only)
           float* __restrict__ parts) {
    constexpr int O   = DEFORM ? 256 : 128;
    constexpr int PWN = DEFORM ? 4 : 2;             // p-frags per wave
    __shared__ unsigned short Bs[64 * 64] __attribute__((aligned(16)));

    const int t = threadIdx.x;
    const int wave = t >> 6, lane = t & 63;
    const int q = lane >> 4, r = lane & 15;

    // ---- XCD-chunked swizzle (neutral R5; kept — grid (128,4)) ----
    const int bid = blockIdx.x + (blockIdx.y << 7);
    const int xcd = bid & 7;
    const int idx = bid >> 3;
    const int pt  = (xcd << 4) | (idx & 15);
    const int ks  = idx >> 4;
    const int pbase = pt * 64;
    const int kstart = ks * KSL;

    const int obw = DEFORM ? (wave * 64) : ((wave >> 1) * 64);
    const int pfb = DEFORM ? 0 : ((wave & 1) * 32);

    // staging coords: thread -> (p_local = t>>2, 16 channels at csub)
    const int pl = t >> 2;
    const int csub = (t & 3) * 16;
    const int p = pbase + pl;
    const int z = p >> 10, y = (p >> 5) & 31, xx = p & 31;
    const int g0 = (t & 3) * 2;
    const int wr0 = pl * 64 + ((g0 ^ (pl & 7)) << 3);
    const int wr1 = pl * 64 + (((g0 + 1) ^ (pl & 7)) << 3);

    facc_t acc[4][PWN];
#pragma unroll
    for (int i = 0; i < 4; ++i)
#pragma unroll
        for (int ip = 0; ip < PWN; ++ip) acc[i][ip] = (facc_t){0.f, 0.f, 0.f, 0.f};

    float cw[8];
    int row0 = 0;
    int ktap = -1;
    ub8_t stv[16];                                  // deform: in-flight gather registers
    ub8_t scv0, scv1;                               // conv: in-flight row registers
    float dn0 = 0.f, dn1 = 0.f, dn2 = 0.f, dn3 = 0.f; // prefetched dbuf for tap ktap+1

    // compute cw[]/row0 for tap k_s from given offset/mask values
    auto comp_tap = [&](int k_s, float od, float oh, float ow_, float m) {
        const int kd = k_s / 9, kh = (k_s / 3) % 3, kw = k_s % 3;
        float cd = (float)(z + kd - 1) + od;
        float ch = (float)(y + kh - 1) + oh;
        float cx = (float)(xx + kw - 1) + ow_;
        float fdf = floorf(cd), fhf = floorf(ch), fwf = floorf(cx);
        float fd = cd - fdf, fh = ch - fhf, fw = cx - fwf;
        float wz0 = 1.f - fd, wz1 = fd;
        float wy0 = 1.f - fh, wy1 = fh;
        float wx0 = 1.f - fw, wx1 = fw;
        int id, ih, iw;
        if (fdf < -1.f || fdf >= 8.f)  { wz0 = 0.f; wz1 = 0.f; id = 0; } else id = (int)fdf;
        if (fhf < -1.f || fhf >= 32.f) { wy0 = 0.f; wy1 = 0.f; ih = 0; } else ih = (int)fhf;
        if (fwf < -1.f || fwf >= 32.f) { wx0 = 0.f; wx1 = 0.f; iw = 0; } else iw = (int)fwf;
        wz0 *= m; wz1 *= m;
        float w00 = wz0 * wy0, w01 = wz0 * wy1, w10 = wz1 * wy0, w11 = wz1 * wy1;
        cw[0] = w00 * wx0; cw[1] = w00 * wx1;
        cw[2] = w01 * wx0; cw[3] = w01 * wx1;
        cw[4] = w10 * wx0; cw[5] = w10 * wx1;
        cw[6] = w11 * wx0; cw[7] = w11 * wx1;
        row0 = (id + 1) * XP_SZ + (ih + 1) * XP_SY + (iw + 1);
    };
    // prefetch dbuf scalars for tap kn (consumed ~4 chunks later)
    auto pref_tap = [&](int kn) {
        dn0 = dbuf[(3 * kn + 0) * NPOS + p];
        dn1 = dbuf[(3 * kn + 1) * NPOS + p];
        dn2 = dbuf[(3 * kn + 2) * NPOS + p];
        dn3 = dbuf[(81 + kn) * NPOS + p];
    };
    // issue the 16 gathers for channel base c0_s of the current tap
    auto issue_gathers = [&](int c0_s) {
        const unsigned short* cb = Xp + (size_t)row0 * 256 + c0_s + csub;
#pragma unroll
        for (int j = 0; j < 8; ++j) {
            const int roff = ((j >> 2) & 1) * XP_SZ + ((j >> 1) & 1) * XP_SY + (j & 1);
            stv[2 * j]     = *(const ub8_t*)(cb + roff * 256);
            stv[2 * j + 1] = *(const ub8_t*)(cb + roff * 256 + 8);
        }
    };
    // conv: issue next chunk's row loads into registers
    auto conv_issue = [&](int kc_s) {
        const int k_s = kc_s >> 8, c0_s = kc_s & 255;
        const int kd = k_s / 9, kh = (k_s / 3) % 3, kw = k_s % 3;
        const int row = (z + kd) * XP_SZ + (y + kh) * XP_SY + (xx + kw);
        scv0 = *(const ub8_t*)&Xp[(size_t)row * 256 + c0_s + csub];
        scv1 = *(const ub8_t*)&Xp[(size_t)row * 256 + c0_s + csub + 8];
    };

    if (DEFORM) {
        ktap = kstart >> 8;
        comp_tap(ktap, dbuf[(3 * ktap + 0) * NPOS + p], dbuf[(3 * ktap + 1) * NPOS + p],
                 dbuf[(3 * ktap + 2) * NPOS + p], dbuf[(81 + ktap) * NPOS + p]);
        pref_tap(ktap + 1 > 26 ? 26 : ktap + 1);
        issue_gathers(kstart & 255);
    } else {
        conv_issue(kstart);
    }

    for (int chunk = 0; chunk < NCHUNK; ++chunk) {
        const int kc0 = kstart + chunk * 64;
        const int c0 = kc0 & 255; (void)c0;

        // ---- A-fragments (L2-resident weights) ----
        bf8_t afr[2][4];
#pragma unroll
        for (int sl = 0; sl < 2; ++sl)
#pragma unroll
            for (int i = 0; i < 4; ++i)
                afr[sl][i] = *(const bf8_t*)&wt[(size_t)(obw + i * 16 + r) * KTOT + kc0 + sl * 32 + q * 8];

        // ---- B staging ----
        if (DEFORM) {
            // blend this chunk's prefetched gathers
            float av[16];
#pragma unroll
            for (int e = 0; e < 16; ++e) av[e] = 0.f;
#pragma unroll
            for (int j = 0; j < 8; ++j) {
#pragma unroll
                for (int e = 0; e < 8; ++e) {
                    av[e]     += cw[j] * bf2f(stv[2 * j][e]);
                    av[8 + e] += cw[j] * bf2f(stv[2 * j + 1][e]);
                }
            }
            ub8_t v0, v1;
#pragma unroll
            for (int e = 0; e < 8; ++e) { v0[e] = f2bf(av[e]); v1[e] = f2bf(av[8 + e]); }
            // issue next chunk's gathers (they stay in flight across barriers/MFMA)
            if (chunk + 1 < NCHUNK) {
                const int kc1 = kc0 + 64;
                const int k1 = kc1 >> 8;
                if (k1 != ktap) {
                    ktap = k1;
                    comp_tap(k1, dn0, dn1, dn2, dn3);       // uses prefetched scalars
                    pref_tap(k1 + 1 > 26 ? 26 : k1 + 1);    // prefetch following tap
                }
                issue_gathers(kc1 & 255);
            }
            *(ub8_t*)&Bs[wr0] = v0;
            *(ub8_t*)&Bs[wr1] = v1;
        } else {
            // write prefetched rows (loads long complete), then issue next chunk
            *(ub8_t*)&Bs[wr0] = scv0;
            *(ub8_t*)&Bs[wr1] = scv1;
            if (chunk + 1 < NCHUNK) conv_issue(kc0 + 64);
        }

        // ---- barrier WITHOUT vmcnt drain ----
        asm volatile("s_waitcnt lgkmcnt(0)" ::: "memory");
        __builtin_amdgcn_s_barrier();
        __builtin_amdgcn_sched_barrier(0);

        // ---- MFMA ----
#pragma unroll
        for (int sl = 0; sl < 2; ++sl) {
            bf8_t bfr[PWN];
#pragma unroll
            for (int ip = 0; ip < PWN; ++ip) {
                int brow = pfb + ip * 16 + r;
                bfr[ip] = *(const bf8_t*)&Bs[brow * 64 + (((sl * 4 + q) ^ (brow & 7)) << 3)];
            }
#pragma unroll
            for (int i = 0; i < 4; ++i)
#pragma unroll
                for (int ip = 0; ip < PWN; ++ip)
                    acc[i][ip] = __builtin_amdgcn_mfma_f32_16x16x32_bf16(afr[sl][i], bfr[ip], acc[i][ip], 0, 0, 0);
        }

        __builtin_amdgcn_s_barrier();
        __builtin_amdgcn_sched_barrier(0);
    }

    // ---- epilogue: fp32 partials; C/D map row(o)=q*4+reg, col(p)=r [R1/R2-verified] ----
    float* pp = parts + (size_t)ks * O * NPOS;
#pragma unroll
    for (int i = 0; i < 4; ++i)
#pragma unroll
        for (int ip = 0; ip < PWN; ++ip)
#pragma unroll
            for (int reg = 0; reg < 4; ++reg) {
                int o = obw + i * 16 + q * 4 + reg;
                int px = pbase + pfb + ip * 16 + r;
                pp[(size_t)o * NPOS + px] = acc[i][ip][reg];
            }
}

// ---------------- combine conv partials -> dbuf (bias + sigmoid on o>=81) ----------------
__global__ __launch_bounds__(256) void ccombine(const float* __restrict__ parts,
                                                const float* __restrict__ ob,
                                                float* __restrict__ dbuf) {
    int b = blockIdx.x;                 // 108*8
    int o = b >> 3;
    int p4 = ((b & 7) * 256 + threadIdx.x) * 4;
    float s0 = 0, s1 = 0, s2 = 0, s3 = 0;
#pragma unroll
    for (int s = 0; s < KS; ++s) {
        const float4 v = *(const float4*)&parts[((size_t)(s * 128 + o)) * NPOS + p4];
        s0 += v.x; s1 += v.y; s2 += v.z; s3 += v.w;
    }
    float bv = ob[o];
    s0 += bv; s1 += bv; s2 += bv; s3 += bv;
    if (o >= 81) {
        s0 = 1.f / (1.f + __expf(-s0));
        s1 = 1.f / (1.f + __expf(-s1));
        s2 = 1.f / (1.f + __expf(-s2));
        s3 = 1.f / (1.f + __expf(-s3));
    }
    *(float4*)&dbuf[(size_t)o * NPOS + p4] = make_float4(s0, s1, s2, s3);
}

// ---------------- combine deform partials -> relu bf16, transposed into XpB interior ----------------
__global__ __launch_bounds__(256) void dcombine_h(const float* __restrict__ parts,
                                                  const float* __restrict__ bias,
                                                  unsigned short* __restrict__ XpB) {
    __shared__ unsigned short T[64 * 66];
    int p0 = blockIdx.x * 64, o0 = blockIdx.y * 64;
    int t = threadIdx.x;
    int pl = t & 63, og = t >> 6;
#pragma unroll 4
    for (int j = 0; j < 16; ++j) {
        int ol = og * 16 + j;
        float s = 0.f;
#pragma unroll
        for (int sp = 0; sp < KS; ++sp)
            s += parts[((size_t)(sp * 256 + o0 + ol)) * NPOS + p0 + pl];
        s += bias[o0 + ol];
        T[ol * 66 + pl] = f2bf(fmaxf(s, 0.f));
    }
    __syncthreads();
    int c = t & 63, pr = t >> 6;
#pragma unroll 4
    for (int j = 0; j < 16; ++j) {
        int pl2 = j * 4 + pr;
        int pg = p0 + pl2;
        int zz = pg >> 10, yy = (pg >> 5) & 31, xv = pg & 31;
        int row = (zz + 1) * XP_SZ + (yy + 1) * XP_SY + xv + 1;
        XpB[(size_t)row * 256 + o0 + c] = T[c * 66 + pl2];
    }
}

// ---------------- final combine -> fp32 o-major output (bias only) ----------------
__global__ __launch_bounds__(256) void dcombine_out(const float* __restrict__ parts,
                                                    const float* __restrict__ bias,
                                                    float* __restrict__ out) {
    int b = blockIdx.x;                 // 256*8
    int o = b >> 3;
    int p4 = ((b & 7) * 256 + threadIdx.x) * 4;
    float s0 = 0, s1 = 0, s2 = 0, s3 = 0;
#pragma unroll
    for (int s = 0; s < KS; ++s) {
        const float4 v = *(const float4*)&parts[((size_t)(s * 256 + o)) * NPOS + p4];
        s0 += v.x; s1 += v.y; s2 += v.z; s3 += v.w;
    }
    float bv = bias[o];
    *(float4*)&out[(size_t)o * NPOS + p4] = make_float4(s0 + bv, s1 + bv, s2 + bv, s3 + bv);
}

// ---------------- host orchestration ----------------
extern "C" void kernel_launch(void* const* d_in, const int* in_sizes, int n_in,
                              void* d_out, int out_size, void* d_ws, size_t ws_size,
                              hipStream_t stream) {
    const float* x      = (const float*)d_in[0];
    const float* ow1    = (const float*)d_in[1];
    const float* ob1    = (const float*)d_in[2];
    const float* w1     = (const float*)d_in[3];
    const float* b1     = (const float*)d_in[4];
    const float* ow2    = (const float*)d_in[5];
    const float* ob2    = (const float*)d_in[6];
    const float* w2     = (const float*)d_in[7];
    const float* b2     = (const float*)d_in[8];
    const float* ow3    = (const float*)d_in[9];
    const float* ob3    = (const float*)d_in[10];
    const float* w3     = (const float*)d_in[11];
    const float* b3     = (const float*)d_in[12];
    const float* defo_w = (const float*)d_in[13];
    const float* defo_b = (const float*)d_in[14];
    const float* c3d_w  = (const float*)d_in[15];
    const float* c3d_b  = (const float*)d_in[16];
    float* out = (float*)d_out;

    // workspace carve-up (~70 MB)
    unsigned short* XpA    = (unsigned short*)d_ws;          // 2,959,360 us
    unsigned short* XpB    = XpA + (size_t)XP_ROWS * 256;    // 2,959,360 us (adjacent for zero_k)
    unsigned short* wtoff  = XpB + (size_t)XP_ROWS * 256;    // 4*128*6912
    unsigned short* wtmain = wtoff + (size_t)4 * 128 * KTOT; // 4*256*6912
    float* dbufp = (float*)(wtmain + (size_t)4 * 256 * KTOT);// 108*8192 fp32
    float* parts = dbufp + (size_t)108 * NPOS;               // KS*256*8192 fp32

    const dim3 blk(256);
    const dim3 gG(128, KS);

    zero_k<<<2890, blk, 0, stream>>>(XpA);                   // zeros XpA + XpB
    pad_x_t<<<256, blk, 0, stream>>>(x, XpA);
    wtrans_all<<<1536, blk, 0, stream>>>(ow1, ow2, ow3, defo_w, w1, w2, w3, c3d_w, wtoff, wtmain);

    const float* cbias[4] = {ob1, ob2, ob3, defo_b};
    const float* dbias[4] = {b1, b2, b3, c3d_b};

    for (int L = 0; L < 4; ++L) {
        const unsigned short* featConv = (L == 0) ? XpA : XpB;          // conv input = h_{L-1}
        const unsigned short* featDef  = (L == 3) ? XpA : featConv;     // final deform samples original x
        fgemm<false><<<gG, blk, 0, stream>>>(featConv, wtoff + (size_t)L * 128 * KTOT, nullptr, parts);
        ccombine<<<864, blk, 0, stream>>>(parts, cbias[L], dbufp);
        fgemm<true><<<gG, blk, 0, stream>>>(featDef, wtmain + (size_t)L * 256 * KTOT, dbufp, parts);
        if (L < 3) dcombine_h<<<dim3(128, 4), blk, 0, stream>>>(parts, dbias[L], XpB);
        else       dcombine_out<<<2048, blk, 0, stream>>>(parts, dbias[L], out);
    }
}